// Round 6
// baseline (168.420 us; speedup 1.0000x reference)
//
#include <hip/hip_runtime.h>
#include <hip/hip_bf16.h>

typedef __attribute__((ext_vector_type(8))) short short8;
typedef __attribute__((ext_vector_type(4))) float f32x4;

#define MFMA16(a, b, c) __builtin_amdgcn_mfma_f32_16x16x32_bf16((a), (b), (c), 0, 0, 0)

constexpr int Bc = 2, Lc = 2048, Hc = 16, Ec = 64;
constexpr float SCALE = 0.125f;               // 1/sqrt(64), exact in bf16
constexpr float LOG2E = 1.4426950408889634f;
constexpr float NEGBIG = -3.0e38f;

union SW { short8 s8; unsigned u[4]; float4 f4; };

__device__ __forceinline__ unsigned cvtpk(float lo, float hi) {
  unsigned r;
  asm("v_cvt_pk_bf16_f32 %0, %1, %2" : "=v"(r) : "v"(lo), "v"(hi));
  return r;
}

template <int CTRL>
__device__ __forceinline__ float dppmax(float x) {
  int xi = __builtin_bit_cast(int, x);
  int yi = __builtin_amdgcn_update_dpp(xi, xi, CTRL, 0xF, 0xF, false);
  return fmaxf(x, __builtin_bit_cast(float, yi));
}

__global__ __launch_bounds__(512, 4)
void attn_fwd(const float* __restrict__ Qg, const float* __restrict__ Kg,
              const float* __restrict__ Vg, float* __restrict__ Og) {
  // smem (shorts):
  //  [0,8192):      kt dbuf: [64 s][64 e] bf16, idx ^ ((row&7)<<3)
  //  [8192,16384):  vt dbuf: [64 e][64 s] bf16, s-chunk slot = chunk ^ (e&7)
  //  [16384,20480): pt per wave [16][32], k-chunk slot = chunk ^ (q16>>2)
  __shared__ __align__(16) short smem[20480];

  // ---- causal fold: block owns q-tile pair (i, 31-i): exactly 33 rounds ----
  const int bid = blockIdx.x;
  const int pair = bid & 15;        // 0..15
  const int bh = bid >> 4;          // 0..31
  const int h = bh & (Hc - 1);
  const int b = bh >> 4;
  const int iLo = pair;
  const int QbL = iLo * 64;
  const int QbH = (31 - pair) * 64;

  const int t = threadIdx.x;
  const int w = t >> 6;        // 0..7
  const int qsub = w & 3;      // q sub-block
  const int par = w >> 2;      // s parity within the 64-row staging tile
  const int l = t & 63;
  const int n = l & 15;
  const int g = l >> 4;

  short* pt = smem + 16384 + w * 512;

  short8 onesv;
  #pragma unroll
  for (int j = 0; j < 8; ++j) onesv[j] = (short)0x3F80;  // bf16 1.0
  const f32x4 zero4 = {0.f, 0.f, 0.f, 0.f};

  // ---- Q fragments for both tiles (A-layout: row=n, k=g*8+j), scale folded ----
  auto loadq = [&](int Qb, short8 (&qf)[2]) {
    const int q = Qb + qsub * 16 + n;
    const float* qp = Qg + ((size_t)(b * Lc + q) * Hc + h) * Ec + g * 8;
    SW a0, a1, b0, b1, r0, r1;
    a0.f4 = reinterpret_cast<const float4*>(qp)[0];
    a1.f4 = reinterpret_cast<const float4*>(qp)[1];
    b0.f4 = reinterpret_cast<const float4*>(qp + 32)[0];
    b1.f4 = reinterpret_cast<const float4*>(qp + 32)[1];
    r0.u[0] = cvtpk(a0.f4.x * SCALE, a0.f4.y * SCALE);
    r0.u[1] = cvtpk(a0.f4.z * SCALE, a0.f4.w * SCALE);
    r0.u[2] = cvtpk(a1.f4.x * SCALE, a1.f4.y * SCALE);
    r0.u[3] = cvtpk(a1.f4.z * SCALE, a1.f4.w * SCALE);
    r1.u[0] = cvtpk(b0.f4.x * SCALE, b0.f4.y * SCALE);
    r1.u[1] = cvtpk(b0.f4.z * SCALE, b0.f4.w * SCALE);
    r1.u[2] = cvtpk(b1.f4.x * SCALE, b1.f4.y * SCALE);
    r1.u[3] = cvtpk(b1.f4.z * SCALE, b1.f4.w * SCALE);
    qf[0] = r0.s8;
    qf[1] = r1.s8;
  };
  short8 qfL[2], qfH[2];
  loadq(QbL, qfL);
  loadq(QbH, qfH);

  f32x4 accL[4] = {zero4, zero4, zero4, zero4};
  f32x4 accH[4] = {zero4, zero4, zero4, zero4};
  float mL[4] = {NEGBIG, NEGBIG, NEGBIG, NEGBIG};
  float mH[4] = {NEGBIG, NEGBIG, NEGBIG, NEGBIG};
  float lL[4] = {0.f, 0.f, 0.f, 0.f};
  float lH[4] = {0.f, 0.f, 0.f, 0.f};

  // staging coordinates: 512 threads stage 64 rows of K and V^T per round
  const int srow = t >> 3, sc8 = (t & 7) * 8;  // K: row 0..63, 8 cols
  const int ve = l, vs0 = w * 8;               // V^T: col e = lane, 8 s rows

  float4 ka, kb;
  float va[8];

  auto issue = [&](int r0) {
    const float* kp = Kg + ((size_t)(b * Lc + r0 + srow) * Hc + h) * Ec + sc8;
    ka = reinterpret_cast<const float4*>(kp)[0];
    kb = reinterpret_cast<const float4*>(kp)[1];
    const float* vp = Vg + ((size_t)(b * Lc + r0 + vs0) * Hc + h) * Ec + ve;
    #pragma unroll
    for (int j = 0; j < 8; ++j) va[j] = vp[(size_t)j * (Hc * Ec)];
  };
  auto commit = [&](int buf) {
    SW kv;
    kv.u[0] = cvtpk(ka.x, ka.y); kv.u[1] = cvtpk(ka.z, ka.w);
    kv.u[2] = cvtpk(kb.x, kb.y); kv.u[3] = cvtpk(kb.z, kb.w);
    *reinterpret_cast<short8*>(&smem[buf * 4096 + ((srow * 64 + sc8) ^ ((srow & 7) << 3))]) = kv.s8;
    SW vv;
    vv.u[0] = cvtpk(va[0], va[1]); vv.u[1] = cvtpk(va[2], va[3]);
    vv.u[2] = cvtpk(va[4], va[5]); vv.u[3] = cvtpk(va[6], va[7]);
    *reinterpret_cast<short8*>(&smem[8192 + buf * 4096 + ve * 64 + ((w ^ (ve & 7)) << 3)]) = vv.s8;
  };

  // ---- one 64q x 64s round for the given tile state ----
  auto round = [&](int Qb, const short8 (&qf)[2], f32x4 (&acc)[4],
                   float (&mrun)[4], float (&lrun)[4], int s0, int curb) {
    const int sbase = s0 + par * 32;
    if (sbase > Qb + qsub * 16 + 15) return;

    // QK^T: scores[16 q][32 s]
    f32x4 sc[2] = {zero4, zero4};
    #pragma unroll
    for (int cc = 0; cc < 2; ++cc) {
      #pragma unroll
      for (int cb = 0; cb < 2; ++cb) {
        const int row = par * 32 + cb * 16 + n;
        const int idx = curb * 4096 + ((row * 64 + cc * 32 + g * 8) ^ ((n & 7) << 3));
        short8 kf = *reinterpret_cast<const short8*>(&smem[idx]);
        sc[cb] = MFMA16(qf[cc], kf, sc[cb]);
      }
    }

    // mask + row max (C layout: row q16 = g*4+r, col s16 = n)
    float s_f[2][4];
    const bool domask = (sbase + 31) > (Qb + qsub * 16);
    #pragma unroll
    for (int cb = 0; cb < 2; ++cb) {
      #pragma unroll
      for (int r = 0; r < 4; ++r) {
        float v = sc[cb][r];
        if (domask) {
          const int s = sbase + cb * 16 + n;
          const int q = Qb + qsub * 16 + g * 4 + r;
          if (s > q) v = NEGBIG;
        }
        s_f[cb][r] = v;
      }
    }
    float mx[4];
    #pragma unroll
    for (int r = 0; r < 4; ++r) mx[r] = fmaxf(s_f[0][r], s_f[1][r]);
    #pragma unroll
    for (int r = 0; r < 4; ++r) mx[r] = dppmax<0xB1>(mx[r]);
    #pragma unroll
    for (int r = 0; r < 4; ++r) mx[r] = dppmax<0x4E>(mx[r]);
    #pragma unroll
    for (int r = 0; r < 4; ++r) mx[r] = dppmax<0x141>(mx[r]);
    #pragma unroll
    for (int r = 0; r < 4; ++r) mx[r] = dppmax<0x140>(mx[r]);

    // exact-identity rescale skip: if no row max grew, afac == 1 exactly
    const int nochg = (mx[0] <= mrun[0]) && (mx[1] <= mrun[1]) &&
                      (mx[2] <= mrun[2]) && (mx[3] <= mrun[3]);
    const bool resc = !__all(nochg);
    float afac[4];
    if (resc) {
      #pragma unroll
      for (int r = 0; r < 4; ++r) {
        const float mn = fmaxf(mrun[r], mx[r]);
        afac[r] = exp2f((mrun[r] - mn) * LOG2E);
        mrun[r] = mn;
      }
    }

    // P -> bf16 -> pt (k-chunk swizzled)
    #pragma unroll
    for (int cb = 0; cb < 2; ++cb) {
      float p0 = exp2f((s_f[cb][0] - mrun[0]) * LOG2E);
      float p1 = exp2f((s_f[cb][1] - mrun[1]) * LOG2E);
      float p2 = exp2f((s_f[cb][2] - mrun[2]) * LOG2E);
      float p3 = exp2f((s_f[cb][3] - mrun[3]) * LOG2E);
      unsigned u01 = cvtpk(p0, p1);
      unsigned u23 = cvtpk(p2, p3);
      const int slot = (cb * 2 + (n >> 3)) ^ g;
      const int base = slot * 8 + (n & 7);
      pt[(g * 4 + 0) * 32 + base] = (short)(u01 & 0xffff);
      pt[(g * 4 + 1) * 32 + base] = (short)(u01 >> 16);
      pt[(g * 4 + 2) * 32 + base] = (short)(u23 & 0xffff);
      pt[(g * 4 + 3) * 32 + base] = (short)(u23 >> 16);
    }
    asm volatile("s_waitcnt lgkmcnt(0)" ::: "memory");
    const int rslot = g ^ ((n >> 2) & 3);
    short8 pf = *reinterpret_cast<const short8*>(&pt[n * 32 + (rslot << 3)]);

    // row sums via ones-MFMA
    f32x4 rs = MFMA16(pf, onesv, zero4);
    if (resc) {
      #pragma unroll
      for (int r = 0; r < 4; ++r) lrun[r] = lrun[r] * afac[r] + rs[r];
      #pragma unroll
      for (int e4 = 0; e4 < 4; ++e4) {
        #pragma unroll
        for (int r = 0; r < 4; ++r) acc[e4][r] *= afac[r];
      }
    } else {
      #pragma unroll
      for (int r = 0; r < 4; ++r) lrun[r] += rs[r];
    }

    // PV: B-frag = ds_read_b128 from V^T (this parity's s-chunks)
    #pragma unroll
    for (int e4 = 0; e4 < 4; ++e4) {
      const int e = e4 * 16 + n;
      const int slot = (par * 4 + g) ^ (e & 7);
      short8 vf = *reinterpret_cast<const short8*>(
          &smem[8192 + curb * 4096 + e * 64 + (slot << 3)]);
      acc[e4] = MFMA16(pf, vf, acc[e4]);
    }
  };

  // ---- fused 33-round stream: rounds 0..iLo on tile lo, rest on tile hi ----
  constexpr int NRO = 33;
  issue(0);
  commit(0);
  __syncthreads();

  int cur = 0;
  for (int rd = 0; rd < NRO; ++rd) {
    const bool pre = (rd + 1 < NRO);
    if (pre) {
      const int nrd = rd + 1;
      const int nstr = (nrd <= iLo) ? nrd : nrd - iLo - 1;
      issue(nstr * 64);
    }
    if (rd <= iLo) round(QbL, qfL, accL, mL, lL, rd * 64, cur);
    else           round(QbH, qfH, accH, mH, lH, (rd - iLo - 1) * 64, cur);
    if (pre) commit(cur ^ 1);
    __syncthreads();
    cur ^= 1;
  }

  // ---- merge parities via LDS scratch, store (once per tile) ----
  float* mb = reinterpret_cast<float*>(smem);
  auto merge_store = [&](int Qb, f32x4 (&acc)[4], float (&mrun)[4], float (&lrun)[4]) {
    __syncthreads();
    if (par == 1) {
      #pragma unroll
      for (int e4 = 0; e4 < 4; ++e4)
        #pragma unroll
        for (int r = 0; r < 4; ++r)
          mb[(qsub * 16 + g * 4 + r) * 64 + e4 * 16 + n] = acc[e4][r];
      if (n == 0) {
        #pragma unroll
        for (int r = 0; r < 4; ++r) {
          mb[4096 + qsub * 16 + g * 4 + r] = mrun[r];
          mb[4160 + qsub * 16 + g * 4 + r] = lrun[r];
        }
      }
    }
    __syncthreads();
    if (par == 0) {
      #pragma unroll
      for (int r = 0; r < 4; ++r) {
        const int q16 = g * 4 + r;
        const float m1 = mb[4096 + qsub * 16 + q16];
        const float l1 = mb[4160 + qsub * 16 + q16];
        const float mm = fmaxf(mrun[r], m1);
        const float a0 = exp2f((mrun[r] - mm) * LOG2E);
        const float a1 = exp2f((m1 - mm) * LOG2E);
        const float inv = 1.0f / (lrun[r] * a0 + l1 * a1);
        const int q = Qb + qsub * 16 + q16;
        float* op = Og + ((size_t)(b * Lc + q) * Hc + h) * Ec + n;
        #pragma unroll
        for (int e4 = 0; e4 < 4; ++e4)
          op[e4 * 16] = (acc[e4][r] * a0 + mb[(qsub * 16 + q16) * 64 + e4 * 16 + n] * a1) * inv;
      }
    }
  };
  merge_store(QbL, accL, mL, lL);
  merge_store(QbH, accH, mH, lH);
}

extern "C" void kernel_launch(void* const* d_in, const int* in_sizes, int n_in,
                              void* d_out, int out_size, void* d_ws, size_t ws_size,
                              hipStream_t stream) {
  const float* Q = (const float*)d_in[0];
  const float* K = (const float*)d_in[1];
  const float* V = (const float*)d_in[2];
  float* O = (float*)d_out;
  dim3 grid(Bc * Hc * 16);   // 32 bh x 16 folded pairs
  attn_fwd<<<grid, dim3(512), 0, stream>>>(Q, K, V, O);
}

// Round 7
// 96.654 us; speedup vs baseline: 1.7425x; 1.7425x over previous
//
#include <hip/hip_runtime.h>
#include <hip/hip_bf16.h>

typedef __attribute__((ext_vector_type(8))) short short8;
typedef __attribute__((ext_vector_type(4))) float f32x4;

#define MFMA16(a, b, c) __builtin_amdgcn_mfma_f32_16x16x32_bf16((a), (b), (c), 0, 0, 0)

constexpr int Bc = 2, Lc = 2048, Hc = 16, Ec = 64;
constexpr float SCALE = 0.125f;               // 1/sqrt(64), exact in bf16
constexpr float LOG2E = 1.4426950408889634f;
constexpr float NEGBIG = -3.0e38f;

union SW { short8 s8; unsigned u[4]; float4 f4; };

__device__ __forceinline__ unsigned cvtpk(float lo, float hi) {
  unsigned r;
  asm("v_cvt_pk_bf16_f32 %0, %1, %2" : "=v"(r) : "v"(lo), "v"(hi));
  return r;
}

template <int CTRL>
__device__ __forceinline__ float dppmax(float x) {
  int xi = __builtin_bit_cast(int, x);
  int yi = __builtin_amdgcn_update_dpp(xi, xi, CTRL, 0xF, 0xF, false);
  return fmaxf(x, __builtin_bit_cast(float, yi));
}

__global__ __launch_bounds__(512, 4)
void attn_fwd(const float* __restrict__ Qg, const float* __restrict__ Kg,
              const float* __restrict__ Vg, float* __restrict__ Og) {
  // smem (shorts):
  //  [0,8192):      kt dbuf: [64 s][64 e] bf16, idx ^ ((row&7)<<3)
  //  [8192,16384):  vt dbuf: [64 e][64 s] bf16, s-chunk slot = chunk ^ (e&7)
  //  [16384,20480): pt per wave [16][32], k-chunk slot = chunk ^ (q16>>2)
  __shared__ __align__(16) short smem[20480];
  // separate merge scratch so mid-loop merge doesn't clobber staged K/V
  __shared__ __align__(16) float mscr[4224];   // acc 64x64 + m 64 + l 64

  // ---- causal fold: block owns q-tile pair (i, 31-i): exactly 33 rounds ----
  const int bid = blockIdx.x;
  const int pair = bid & 15;        // 0..15
  const int bh = bid >> 4;          // 0..31
  const int h = bh & (Hc - 1);
  const int b = bh >> 4;
  const int iLo = pair;
  const int QbL = iLo * 64;
  const int QbH = (31 - pair) * 64;

  const int t = threadIdx.x;
  const int w = t >> 6;        // 0..7
  const int qsub = w & 3;      // q sub-block
  const int par = w >> 2;      // s parity within the 64-row staging tile
  const int l = t & 63;
  const int n = l & 15;
  const int g = l >> 4;

  short* pt = smem + 16384 + w * 512;

  short8 onesv;
  #pragma unroll
  for (int j = 0; j < 8; ++j) onesv[j] = (short)0x3F80;  // bf16 1.0
  const f32x4 zero4 = {0.f, 0.f, 0.f, 0.f};

  // ---- Q fragment loader (A-layout: row=n, k=g*8+j), scale folded ----
  short8 qf[2];
  auto loadq = [&](int Qb) {
    const int q = Qb + qsub * 16 + n;
    const float* qp = Qg + ((size_t)(b * Lc + q) * Hc + h) * Ec + g * 8;
    SW a0, a1, b0, b1, r0, r1;
    a0.f4 = reinterpret_cast<const float4*>(qp)[0];
    a1.f4 = reinterpret_cast<const float4*>(qp)[1];
    b0.f4 = reinterpret_cast<const float4*>(qp + 32)[0];
    b1.f4 = reinterpret_cast<const float4*>(qp + 32)[1];
    r0.u[0] = cvtpk(a0.f4.x * SCALE, a0.f4.y * SCALE);
    r0.u[1] = cvtpk(a0.f4.z * SCALE, a0.f4.w * SCALE);
    r0.u[2] = cvtpk(a1.f4.x * SCALE, a1.f4.y * SCALE);
    r0.u[3] = cvtpk(a1.f4.z * SCALE, a1.f4.w * SCALE);
    r1.u[0] = cvtpk(b0.f4.x * SCALE, b0.f4.y * SCALE);
    r1.u[1] = cvtpk(b0.f4.z * SCALE, b0.f4.w * SCALE);
    r1.u[2] = cvtpk(b1.f4.x * SCALE, b1.f4.y * SCALE);
    r1.u[3] = cvtpk(b1.f4.z * SCALE, b1.f4.w * SCALE);
    qf[0] = r0.s8;
    qf[1] = r1.s8;
  };

  f32x4 acc[4] = {zero4, zero4, zero4, zero4};
  float mrun[4] = {NEGBIG, NEGBIG, NEGBIG, NEGBIG};
  float lrun[4] = {0.f, 0.f, 0.f, 0.f};

  // staging coordinates: 512 threads stage 64 rows of K and V^T per round
  const int srow = t >> 3, sc8 = (t & 7) * 8;  // K: row 0..63, 8 cols
  const int ve = l, vs0 = w * 8;               // V^T: col e = lane, 8 s rows

  float4 ka, kb;
  float va[8];

  auto issue = [&](int r0) {
    const float* kp = Kg + ((size_t)(b * Lc + r0 + srow) * Hc + h) * Ec + sc8;
    ka = reinterpret_cast<const float4*>(kp)[0];
    kb = reinterpret_cast<const float4*>(kp)[1];
    const float* vp = Vg + ((size_t)(b * Lc + r0 + vs0) * Hc + h) * Ec + ve;
    #pragma unroll
    for (int j = 0; j < 8; ++j) va[j] = vp[(size_t)j * (Hc * Ec)];
  };
  auto commit = [&](int buf) {
    SW kv;
    kv.u[0] = cvtpk(ka.x, ka.y); kv.u[1] = cvtpk(ka.z, ka.w);
    kv.u[2] = cvtpk(kb.x, kb.y); kv.u[3] = cvtpk(kb.z, kb.w);
    *reinterpret_cast<short8*>(&smem[buf * 4096 + ((srow * 64 + sc8) ^ ((srow & 7) << 3))]) = kv.s8;
    SW vv;
    vv.u[0] = cvtpk(va[0], va[1]); vv.u[1] = cvtpk(va[2], va[3]);
    vv.u[2] = cvtpk(va[4], va[5]); vv.u[3] = cvtpk(va[6], va[7]);
    *reinterpret_cast<short8*>(&smem[8192 + buf * 4096 + ve * 64 + ((w ^ (ve & 7)) << 3)]) = vv.s8;
  };

  // ---- one 64q x 64s round against the current tile state ----
  auto round = [&](int Qb, int s0, int curb) {
    const int sbase = s0 + par * 32;
    if (sbase > Qb + qsub * 16 + 15) return;

    // QK^T: scores[16 q][32 s]
    f32x4 sc[2] = {zero4, zero4};
    #pragma unroll
    for (int cc = 0; cc < 2; ++cc) {
      #pragma unroll
      for (int cb = 0; cb < 2; ++cb) {
        const int row = par * 32 + cb * 16 + n;
        const int idx = curb * 4096 + ((row * 64 + cc * 32 + g * 8) ^ ((n & 7) << 3));
        short8 kf = *reinterpret_cast<const short8*>(&smem[idx]);
        sc[cb] = MFMA16(qf[cc], kf, sc[cb]);
      }
    }

    // mask + row max (C layout: row q16 = g*4+r, col s16 = n)
    float s_f[2][4];
    const bool domask = (sbase + 31) > (Qb + qsub * 16);
    #pragma unroll
    for (int cb = 0; cb < 2; ++cb) {
      #pragma unroll
      for (int r = 0; r < 4; ++r) {
        float v = sc[cb][r];
        if (domask) {
          const int s = sbase + cb * 16 + n;
          const int q = Qb + qsub * 16 + g * 4 + r;
          if (s > q) v = NEGBIG;
        }
        s_f[cb][r] = v;
      }
    }
    float mx[4];
    #pragma unroll
    for (int r = 0; r < 4; ++r) mx[r] = fmaxf(s_f[0][r], s_f[1][r]);
    #pragma unroll
    for (int r = 0; r < 4; ++r) mx[r] = dppmax<0xB1>(mx[r]);
    #pragma unroll
    for (int r = 0; r < 4; ++r) mx[r] = dppmax<0x4E>(mx[r]);
    #pragma unroll
    for (int r = 0; r < 4; ++r) mx[r] = dppmax<0x141>(mx[r]);
    #pragma unroll
    for (int r = 0; r < 4; ++r) mx[r] = dppmax<0x140>(mx[r]);

    // exact-identity rescale skip: if no row max grew, afac == 1 exactly
    const int nochg = (mx[0] <= mrun[0]) && (mx[1] <= mrun[1]) &&
                      (mx[2] <= mrun[2]) && (mx[3] <= mrun[3]);
    const bool resc = !__all(nochg);
    float afac[4];
    if (resc) {
      #pragma unroll
      for (int r = 0; r < 4; ++r) {
        const float mn = fmaxf(mrun[r], mx[r]);
        afac[r] = exp2f((mrun[r] - mn) * LOG2E);
        mrun[r] = mn;
      }
    }

    // P -> bf16 -> pt (k-chunk swizzled)
    #pragma unroll
    for (int cb = 0; cb < 2; ++cb) {
      float p0 = exp2f((s_f[cb][0] - mrun[0]) * LOG2E);
      float p1 = exp2f((s_f[cb][1] - mrun[1]) * LOG2E);
      float p2 = exp2f((s_f[cb][2] - mrun[2]) * LOG2E);
      float p3 = exp2f((s_f[cb][3] - mrun[3]) * LOG2E);
      unsigned u01 = cvtpk(p0, p1);
      unsigned u23 = cvtpk(p2, p3);
      const int slot = (cb * 2 + (n >> 3)) ^ g;
      const int base = slot * 8 + (n & 7);
      pt[(g * 4 + 0) * 32 + base] = (short)(u01 & 0xffff);
      pt[(g * 4 + 1) * 32 + base] = (short)(u01 >> 16);
      pt[(g * 4 + 2) * 32 + base] = (short)(u23 & 0xffff);
      pt[(g * 4 + 3) * 32 + base] = (short)(u23 >> 16);
    }
    asm volatile("s_waitcnt lgkmcnt(0)" ::: "memory");
    const int rslot = g ^ ((n >> 2) & 3);
    short8 pf = *reinterpret_cast<const short8*>(&pt[n * 32 + (rslot << 3)]);

    // row sums via ones-MFMA
    f32x4 rs = MFMA16(pf, onesv, zero4);
    if (resc) {
      #pragma unroll
      for (int r = 0; r < 4; ++r) lrun[r] = lrun[r] * afac[r] + rs[r];
      #pragma unroll
      for (int e4 = 0; e4 < 4; ++e4) {
        #pragma unroll
        for (int r = 0; r < 4; ++r) acc[e4][r] *= afac[r];
      }
    } else {
      #pragma unroll
      for (int r = 0; r < 4; ++r) lrun[r] += rs[r];
    }

    // PV: B-frag = ds_read_b128 from V^T (this parity's s-chunks)
    #pragma unroll
    for (int e4 = 0; e4 < 4; ++e4) {
      const int e = e4 * 16 + n;
      const int slot = (par * 4 + g) ^ (e & 7);
      short8 vf = *reinterpret_cast<const short8*>(
          &smem[8192 + curb * 4096 + e * 64 + (slot << 3)]);
      acc[e4] = MFMA16(pf, vf, acc[e4]);
    }
  };

  // ---- merge parities via mscr, store, reset state ----
  auto merge_store = [&](int Qb) {
    __syncthreads();
    if (par == 1) {
      #pragma unroll
      for (int e4 = 0; e4 < 4; ++e4)
        #pragma unroll
        for (int r = 0; r < 4; ++r)
          mscr[(qsub * 16 + g * 4 + r) * 64 + e4 * 16 + n] = acc[e4][r];
      if (n == 0) {
        #pragma unroll
        for (int r = 0; r < 4; ++r) {
          mscr[4096 + qsub * 16 + g * 4 + r] = mrun[r];
          mscr[4160 + qsub * 16 + g * 4 + r] = lrun[r];
        }
      }
    }
    __syncthreads();
    if (par == 0) {
      #pragma unroll
      for (int r = 0; r < 4; ++r) {
        const int q16 = g * 4 + r;
        const float m1 = mscr[4096 + qsub * 16 + q16];
        const float l1 = mscr[4160 + qsub * 16 + q16];
        const float mm = fmaxf(mrun[r], m1);
        const float a0 = exp2f((mrun[r] - mm) * LOG2E);
        const float a1 = exp2f((m1 - mm) * LOG2E);
        const float inv = 1.0f / (lrun[r] * a0 + l1 * a1);
        const int q = Qb + qsub * 16 + q16;
        float* op = Og + ((size_t)(b * Lc + q) * Hc + h) * Ec + n;
        #pragma unroll
        for (int e4 = 0; e4 < 4; ++e4)
          op[e4 * 16] = (acc[e4][r] * a0 + mscr[(qsub * 16 + q16) * 64 + e4 * 16 + n] * a1) * inv;
      }
    }
  };

  // ---- fused 33-round stream: rounds 0..iLo on tile lo, rest on tile hi ----
  constexpr int NRO = 33;
  loadq(QbL);
  issue(0);
  commit(0);
  __syncthreads();

  int cur = 0;
  for (int rd = 0; rd < NRO; ++rd) {
    const bool pre = (rd + 1 < NRO);
    if (pre) {
      const int nrd = rd + 1;
      const int nstr = (nrd <= iLo) ? nrd : nrd - iLo - 1;
      issue(nstr * 64);
    }
    const bool lo = (rd <= iLo);
    round(lo ? QbL : QbH, (lo ? rd : rd - iLo - 1) * 64, cur);
    if (rd == iLo) {
      // finish tile lo: merge+store (separate scratch), reset, switch Q
      merge_store(QbL);
      #pragma unroll
      for (int e4 = 0; e4 < 4; ++e4) acc[e4] = zero4;
      #pragma unroll
      for (int r = 0; r < 4; ++r) { mrun[r] = NEGBIG; lrun[r] = 0.f; }
      loadq(QbH);
    }
    if (pre) commit(cur ^ 1);
    __syncthreads();
    cur ^= 1;
  }

  merge_store(QbH);
}

extern "C" void kernel_launch(void* const* d_in, const int* in_sizes, int n_in,
                              void* d_out, int out_size, void* d_ws, size_t ws_size,
                              hipStream_t stream) {
  const float* Q = (const float*)d_in[0];
  const float* K = (const float*)d_in[1];
  const float* V = (const float*)d_in[2];
  float* O = (float*)d_out;
  dim3 grid(Bc * Hc * 16);   // 32 bh x 16 folded pairs, all identical work
  attn_fwd<<<grid, dim3(512), 0, stream>>>(Q, K, V, O);
}

// Round 8
// 91.434 us; speedup vs baseline: 1.8420x; 1.0571x over previous
//
#include <hip/hip_runtime.h>
#include <hip/hip_bf16.h>

typedef __attribute__((ext_vector_type(8))) short short8;
typedef __attribute__((ext_vector_type(4))) float f32x4;

#define MFMA16(a, b, c) __builtin_amdgcn_mfma_f32_16x16x32_bf16((a), (b), (c), 0, 0, 0)

constexpr int Bc = 2, Lc = 2048, Hc = 16, Ec = 64;
constexpr float LOG2E = 1.4426950408889634f;
constexpr float SCALE2 = 0.125f * LOG2E;   // fold log2(e) into Q scale: scores in log2 units
constexpr float NEGBIG = -3.0e38f;

union SW { short8 s8; unsigned u[4]; float4 f4; };

__device__ __forceinline__ unsigned cvtpk(float lo, float hi) {
  unsigned r;
  asm("v_cvt_pk_bf16_f32 %0, %1, %2" : "=v"(r) : "v"(lo), "v"(hi));
  return r;
}
__device__ __forceinline__ float exp2v(float x) {
  float r;
  asm("v_exp_f32 %0, %1" : "=v"(r) : "v"(x));
  return r;
}
__device__ __forceinline__ float bfhi(unsigned u) {
  return __builtin_bit_cast(float, u & 0xffff0000u);
}
__device__ __forceinline__ float bflo(unsigned u) {
  return __builtin_bit_cast(float, u << 16);
}

__global__ __launch_bounds__(512, 4)
void attn_fwd(const float* __restrict__ Qg, const float* __restrict__ Kg,
              const float* __restrict__ Vg, float* __restrict__ Og) {
  // smem (shorts):
  //  [0,8192):     kt dbuf: [64][64] bf16, K row s stored at prow = s with
  //                bits2<->3 swapped (per 16-block), idx ^ ((prow&7)<<3)
  //  [8192,16384): vt dbuf: [64 e][64 s] bf16, s-chunk slot = chunk ^ (e&7)
  __shared__ __align__(16) short smem[16384];
  __shared__ __align__(16) float mscr[4480];   // merge: acc [64][68] + m 64 + l 64

  // causal fold: block owns q-tile pair (i, 31-i): exactly 33 uniform rounds
  const int bid = blockIdx.x;
  const int pair = bid & 15;
  const int bh = bid >> 4;
  const int h = bh & (Hc - 1);
  const int b = bh >> 4;
  const int iLo = pair;
  const int QbL = iLo * 64;
  const int QbH = (31 - pair) * 64;

  const int t = threadIdx.x;
  const int w = t >> 6;        // 0..7
  const int qsub = w & 3;      // q sub-block (16 rows)
  const int par = w >> 2;      // s parity (0: rows 0-31, 1: rows 32-63)
  const int l = t & 63;
  const int n = l & 15;
  const int g = l >> 4;
  const int sp4 = ((g & 1) << 3) | ((g >> 1) << 2);  // pi(g)*4: s-offset of reg block
  const bool glo = (g < 2);

  const f32x4 zero4 = {0.f, 0.f, 0.f, 0.f};

  // Q fragments (usable as B-operand: col=q=lane&15, k=e=(lane>>4)*8+j)
  short8 qf[2];
  auto loadq = [&](int Qb) {
    const int q = Qb + qsub * 16 + n;
    const float* qp = Qg + ((size_t)(b * Lc + q) * Hc + h) * Ec + g * 8;
    SW a0, a1, b0, b1, r0, r1;
    a0.f4 = reinterpret_cast<const float4*>(qp)[0];
    a1.f4 = reinterpret_cast<const float4*>(qp)[1];
    b0.f4 = reinterpret_cast<const float4*>(qp + 32)[0];
    b1.f4 = reinterpret_cast<const float4*>(qp + 32)[1];
    r0.u[0] = cvtpk(a0.f4.x * SCALE2, a0.f4.y * SCALE2);
    r0.u[1] = cvtpk(a0.f4.z * SCALE2, a0.f4.w * SCALE2);
    r0.u[2] = cvtpk(a1.f4.x * SCALE2, a1.f4.y * SCALE2);
    r0.u[3] = cvtpk(a1.f4.z * SCALE2, a1.f4.w * SCALE2);
    r1.u[0] = cvtpk(b0.f4.x * SCALE2, b0.f4.y * SCALE2);
    r1.u[1] = cvtpk(b0.f4.z * SCALE2, b0.f4.w * SCALE2);
    r1.u[2] = cvtpk(b1.f4.x * SCALE2, b1.f4.y * SCALE2);
    r1.u[3] = cvtpk(b1.f4.z * SCALE2, b1.f4.w * SCALE2);
    qf[0] = r0.s8;
    qf[1] = r1.s8;
  };

  // accumulator: acc[e4][r] = O^T[e = e4*16 + g*4 + r][q = n]; per-lane scalar m,l
  f32x4 acc[4] = {zero4, zero4, zero4, zero4};
  float mrun = NEGBIG, lrun = 0.f;

  // staging: 512 threads stage 64 rows of K (pi-permuted) and V^T per round
  const int srow = t >> 3, sc8 = (t & 7) * 8;
  const int prow = (srow & 51) | ((srow & 4) << 1) | ((srow & 8) >> 1);  // swap bits 2,3
  const int ve = l, vs0 = w * 8;

  float4 ka, kb;
  float va[8];

  auto issue = [&](int r0) {
    const float* kp = Kg + ((size_t)(b * Lc + r0 + srow) * Hc + h) * Ec + sc8;
    ka = reinterpret_cast<const float4*>(kp)[0];
    kb = reinterpret_cast<const float4*>(kp)[1];
    const float* vp = Vg + ((size_t)(b * Lc + r0 + vs0) * Hc + h) * Ec + ve;
    #pragma unroll
    for (int j = 0; j < 8; ++j) va[j] = vp[(size_t)j * (Hc * Ec)];
  };
  auto commit = [&](int buf) {
    SW kv;
    kv.u[0] = cvtpk(ka.x, ka.y); kv.u[1] = cvtpk(ka.z, ka.w);
    kv.u[2] = cvtpk(kb.x, kb.y); kv.u[3] = cvtpk(kb.z, kb.w);
    *reinterpret_cast<short8*>(&smem[buf * 4096 + ((prow * 64 + sc8) ^ ((prow & 7) << 3))]) = kv.s8;
    SW vv;
    vv.u[0] = cvtpk(va[0], va[1]); vv.u[1] = cvtpk(va[2], va[3]);
    vv.u[2] = cvtpk(va[4], va[5]); vv.u[3] = cvtpk(va[6], va[7]);
    *reinterpret_cast<short8*>(&smem[8192 + buf * 4096 + ve * 64 + ((w ^ (ve & 7)) << 3)]) = vv.s8;
  };

  // one 64q x 64s round (this wave: 16 q x 32 s half-tile), swapped operands
  auto round = [&](int Qb, int s0, int curb) {
    const int sbase = s0 + par * 32;
    if (sbase > Qb + qsub * 16 + 15) return;

    // QK^T swapped: D[s][q], col = q = n, row-block s = sbase + cb*16 + sp4 + r
    f32x4 sc[2] = {zero4, zero4};
    #pragma unroll
    for (int kc = 0; kc < 2; ++kc) {
      #pragma unroll
      for (int cb = 0; cb < 2; ++cb) {
        const int row = par * 32 + cb * 16 + n;
        const int idx = curb * 4096 + ((row * 64 + kc * 32 + g * 8) ^ ((n & 7) << 3));
        short8 kf = *reinterpret_cast<const short8*>(&smem[idx]);
        sc[cb] = MFMA16(kf, qf[kc], sc[cb]);
      }
    }

    const int qg = Qb + qsub * 16 + n;
    if ((sbase + 31) > (Qb + qsub * 16)) {
      #pragma unroll
      for (int cb = 0; cb < 2; ++cb)
        #pragma unroll
        for (int r = 0; r < 4; ++r)
          if (sbase + cb * 16 + sp4 + r > qg) sc[cb][r] = NEGBIG;
    }

    // row max: 8 lane-local + xor16 + xor32 (all scores for q=n live in 4 lanes)
    float m8 = fmaxf(fmaxf(fmaxf(sc[0][0], sc[0][1]), fmaxf(sc[0][2], sc[0][3])),
                     fmaxf(fmaxf(sc[1][0], sc[1][1]), fmaxf(sc[1][2], sc[1][3])));
    m8 = fmaxf(m8, __shfl_xor(m8, 16));
    m8 = fmaxf(m8, __shfl_xor(m8, 32));

    // exact-identity rescale skip
    const bool resc = !__all(m8 <= mrun);
    if (resc) {
      const float mn = fmaxf(mrun, m8);
      const float afac = exp2v(mrun - mn);
      mrun = mn;
      lrun *= afac;
      #pragma unroll
      for (int e4 = 0; e4 < 4; ++e4)
        #pragma unroll
        for (int r = 0; r < 4; ++r) acc[e4][r] *= afac;
    }

    // P = exp2(S2 - m), packed bf16 pairs (scores already log2-scaled)
    const unsigned u0a = cvtpk(exp2v(sc[0][0] - mrun), exp2v(sc[0][1] - mrun));
    const unsigned u0b = cvtpk(exp2v(sc[0][2] - mrun), exp2v(sc[0][3] - mrun));
    const unsigned u1a = cvtpk(exp2v(sc[1][0] - mrun), exp2v(sc[1][1] - mrun));
    const unsigned u1b = cvtpk(exp2v(sc[1][2] - mrun), exp2v(sc[1][3] - mrun));

    // lane^32 exchange -> B-frag in true s order (k = 8g..8g+7); pi makes ^32 sufficient
    const unsigned x0a = __shfl_xor(u0a, 32);
    const unsigned x0b = __shfl_xor(u0b, 32);
    const unsigned x1a = __shfl_xor(u1a, 32);
    const unsigned x1b = __shfl_xor(u1b, 32);
    SW pw;
    pw.u[0] = glo ? u0a : x1a;
    pw.u[1] = glo ? u0b : x1b;
    pw.u[2] = glo ? x0a : u1a;
    pw.u[3] = glo ? x0b : u1b;

    // PV swapped: acc = V^T x P -> D[e][q], col = q = n (same as softmax lane!)
    #pragma unroll
    for (int e4 = 0; e4 < 4; ++e4) {
      const int e = e4 * 16 + n;
      const int slot = (par * 4 + g) ^ (e & 7);
      short8 vf = *reinterpret_cast<const short8*>(
          &smem[8192 + curb * 4096 + e * 64 + (slot << 3)]);
      acc[e4] = MFMA16(vf, pw.s8, acc[e4]);
    }

    // row sum of the bf16-rounded P (post-exchange words cover all 32 s once)
    float rs = ((bflo(pw.u[0]) + bfhi(pw.u[0])) + (bflo(pw.u[1]) + bfhi(pw.u[1]))) +
               ((bflo(pw.u[2]) + bfhi(pw.u[2])) + (bflo(pw.u[3]) + bfhi(pw.u[3])));
    rs += __shfl_xor(rs, 16);
    rs += __shfl_xor(rs, 32);
    lrun += rs;
  };

  // merge parities via mscr, store O (per lane: q = n, e-chunks contiguous)
  auto merge_store = [&](int Qb) {
    __syncthreads();
    if (par == 1) {
      #pragma unroll
      for (int e4 = 0; e4 < 4; ++e4) {
        const int idx = (qsub * 16 + n) * 68 + e4 * 16 + g * 4;
        #pragma unroll
        for (int r = 0; r < 4; ++r) mscr[idx + r] = acc[e4][r];
      }
      if (g == 0) {
        mscr[4352 + qsub * 16 + n] = mrun;
        mscr[4416 + qsub * 16 + n] = lrun;
      }
    }
    __syncthreads();
    if (par == 0) {
      const float m1 = mscr[4352 + qsub * 16 + n];
      const float l1 = mscr[4416 + qsub * 16 + n];
      const float mm = fmaxf(mrun, m1);
      const float a0 = exp2v(mrun - mm);
      const float a1 = exp2v(m1 - mm);
      const float inv = 1.0f / (lrun * a0 + l1 * a1);
      const int q = Qb + qsub * 16 + n;
      float* op = Og + ((size_t)(b * Lc + q) * Hc + h) * Ec;
      #pragma unroll
      for (int e4 = 0; e4 < 4; ++e4) {
        const int idx = (qsub * 16 + n) * 68 + e4 * 16 + g * 4;
        float4 v;
        v.x = (acc[e4][0] * a0 + mscr[idx + 0] * a1) * inv;
        v.y = (acc[e4][1] * a0 + mscr[idx + 1] * a1) * inv;
        v.z = (acc[e4][2] * a0 + mscr[idx + 2] * a1) * inv;
        v.w = (acc[e4][3] * a0 + mscr[idx + 3] * a1) * inv;
        *reinterpret_cast<float4*>(op + e4 * 16 + g * 4) = v;
      }
    }
  };

  // fused 33-round stream: rounds 0..iLo on tile lo, rest on tile hi
  constexpr int NRO = 33;
  loadq(QbL);
  issue(0);
  commit(0);
  __syncthreads();

  int cur = 0;
  for (int rd = 0; rd < NRO; ++rd) {
    const bool pre = (rd + 1 < NRO);
    if (pre) {
      const int nrd = rd + 1;
      const int nstr = (nrd <= iLo) ? nrd : nrd - iLo - 1;
      issue(nstr * 64);
    }
    const bool lo = (rd <= iLo);
    round(lo ? QbL : QbH, (lo ? rd : rd - iLo - 1) * 64, cur);
    if (rd == iLo) {
      merge_store(QbL);
      #pragma unroll
      for (int e4 = 0; e4 < 4; ++e4) acc[e4] = zero4;
      mrun = NEGBIG;
      lrun = 0.f;
      loadq(QbH);
    }
    if (pre) commit(cur ^ 1);
    __syncthreads();
    cur ^= 1;
  }

  merge_store(QbH);
}

extern "C" void kernel_launch(void* const* d_in, const int* in_sizes, int n_in,
                              void* d_out, int out_size, void* d_ws, size_t ws_size,
                              hipStream_t stream) {
  const float* Q = (const float*)d_in[0];
  const float* K = (const float*)d_in[1];
  const float* V = (const float*)d_in[2];
  float* O = (float*)d_out;
  dim3 grid(Bc * Hc * 16);   // 32 bh x 16 folded pairs, all identical work
  attn_fwd<<<grid, dim3(512), 0, stream>>>(Q, K, V, O);
}

// Round 9
// 90.743 us; speedup vs baseline: 1.8560x; 1.0076x over previous
//
#include <hip/hip_runtime.h>
#include <hip/hip_bf16.h>

typedef __attribute__((ext_vector_type(8))) short short8;
typedef __attribute__((ext_vector_type(4))) float f32x4;

#define MFMA16(a, b, c) __builtin_amdgcn_mfma_f32_16x16x32_bf16((a), (b), (c), 0, 0, 0)

constexpr int Bc = 2, Lc = 2048, Hc = 16, Ec = 64;
constexpr float LOG2E = 1.4426950408889634f;
constexpr float SCALE2 = 0.125f * LOG2E;   // fold log2(e): scores in log2 units
constexpr float NEGBIG = -3.0e38f;

union SW { short8 s8; unsigned u[4]; float4 f4; };

__device__ __forceinline__ unsigned cvtpk(float lo, float hi) {
  unsigned r;
  asm("v_cvt_pk_bf16_f32 %0, %1, %2" : "=v"(r) : "v"(lo), "v"(hi));
  return r;
}
__device__ __forceinline__ float exp2v(float x) {
  float r;
  asm("v_exp_f32 %0, %1" : "=v"(r) : "v"(x));
  return r;
}
__device__ __forceinline__ float bfhi(unsigned u) {
  return __builtin_bit_cast(float, u & 0xffff0000u);
}
__device__ __forceinline__ float bflo(unsigned u) {
  return __builtin_bit_cast(float, u << 16);
}

__global__ __launch_bounds__(512, 4)
void attn_fwd(const float* __restrict__ Qg, const float* __restrict__ Kg,
              const float* __restrict__ Vg, float* __restrict__ Og) {
  // smem (shorts), NT=128 s-tile double-buffered:
  //  kt[b]: [128][64] bf16 at b*8192, K row s at prow=pi(s) (bits2<->3),
  //         idx ^ ((prow&7)<<3)
  //  vt[b]: [64 e][128 s] bf16 at 16384 + b*8192, chunk slot = (s>>3) ^ (e&7)
  // merge scratch overlays the RETIRED buffer (kt[b] rows 0..31, vt[b] rest).
  __shared__ __align__(16) short smem[32768];

  // causal fold: block owns q-tile pair (i, 31-i): exactly 17 uniform rounds
  const int bid = blockIdx.x;
  const int pair = bid & 15;
  const int bh = bid >> 4;
  const int h = bh & (Hc - 1);
  const int b = bh >> 4;
  const int iLo = pair;
  const int QbL = iLo * 64;
  const int QbH = (31 - pair) * 64;
  const int RL = (iLo + 2) >> 1;              // lo-tile rounds; RL + RH = 17

  const int t = threadIdx.x;
  const int w = t >> 6;        // 0..7
  const int qsub = w & 3;      // q sub-block (16 rows)
  const int par = w >> 2;      // 64-s half of the 128-row tile
  const int l = t & 63;
  const int n = l & 15;
  const int g = l >> 4;
  const int sp4 = ((g & 1) << 3) | ((g >> 1) << 2);  // pi(g)*4
  const bool glo = (g < 2);

  const f32x4 zero4 = {0.f, 0.f, 0.f, 0.f};

  // Q fragments (B-operand: col=q=lane&15, k=e=(lane>>4)*8+j)
  short8 qf[2];
  auto loadq = [&](int Qb) {
    const int q = Qb + qsub * 16 + n;
    const float* qp = Qg + ((size_t)(b * Lc + q) * Hc + h) * Ec + g * 8;
    SW a0, a1, b0, b1, r0, r1;
    a0.f4 = reinterpret_cast<const float4*>(qp)[0];
    a1.f4 = reinterpret_cast<const float4*>(qp)[1];
    b0.f4 = reinterpret_cast<const float4*>(qp + 32)[0];
    b1.f4 = reinterpret_cast<const float4*>(qp + 32)[1];
    r0.u[0] = cvtpk(a0.f4.x * SCALE2, a0.f4.y * SCALE2);
    r0.u[1] = cvtpk(a0.f4.z * SCALE2, a0.f4.w * SCALE2);
    r0.u[2] = cvtpk(a1.f4.x * SCALE2, a1.f4.y * SCALE2);
    r0.u[3] = cvtpk(a1.f4.z * SCALE2, a1.f4.w * SCALE2);
    r1.u[0] = cvtpk(b0.f4.x * SCALE2, b0.f4.y * SCALE2);
    r1.u[1] = cvtpk(b0.f4.z * SCALE2, b0.f4.w * SCALE2);
    r1.u[2] = cvtpk(b1.f4.x * SCALE2, b1.f4.y * SCALE2);
    r1.u[3] = cvtpk(b1.f4.z * SCALE2, b1.f4.w * SCALE2);
    qf[0] = r0.s8;
    qf[1] = r1.s8;
  };

  // acc[e4][r] = O^T[e = e4*16 + g*4 + r][q = n]; per-lane scalar m,l
  f32x4 acc[4] = {zero4, zero4, zero4, zero4};
  float mrun = NEGBIG, lrun = 0.f;

  // staging: 512 threads stage 128 rows of K (pi-permuted) and V^T per round
  const int srow = t >> 2;                               // 0..127
  const int prow = (srow & ~12) | ((srow & 4) << 1) | ((srow & 8) >> 1);
  const int kc0 = (t & 3) * 16;                          // 16-float column chunk
  const int ve = l, vs0 = w * 16;                        // V^T: e=lane, 16 s rows

  float4 ka[4];
  float va[16];

  auto issue = [&](int r0) {
    const float* kp = Kg + ((size_t)(b * Lc + r0 + srow) * Hc + h) * Ec + kc0;
    ka[0] = reinterpret_cast<const float4*>(kp)[0];
    ka[1] = reinterpret_cast<const float4*>(kp)[1];
    ka[2] = reinterpret_cast<const float4*>(kp)[2];
    ka[3] = reinterpret_cast<const float4*>(kp)[3];
    const float* vp = Vg + ((size_t)(b * Lc + r0 + vs0) * Hc + h) * Ec + ve;
    #pragma unroll
    for (int j = 0; j < 16; ++j) va[j] = vp[(size_t)j * (Hc * Ec)];
  };
  auto commit = [&](int buf) {
    SW k0, k1;
    k0.u[0] = cvtpk(ka[0].x, ka[0].y); k0.u[1] = cvtpk(ka[0].z, ka[0].w);
    k0.u[2] = cvtpk(ka[1].x, ka[1].y); k0.u[3] = cvtpk(ka[1].z, ka[1].w);
    k1.u[0] = cvtpk(ka[2].x, ka[2].y); k1.u[1] = cvtpk(ka[2].z, ka[2].w);
    k1.u[2] = cvtpk(ka[3].x, ka[3].y); k1.u[3] = cvtpk(ka[3].z, ka[3].w);
    short* kt = smem + buf * 8192;
    *reinterpret_cast<short8*>(&kt[(prow * 64 + kc0) ^ ((prow & 7) << 3)]) = k0.s8;
    *reinterpret_cast<short8*>(&kt[(prow * 64 + kc0 + 8) ^ ((prow & 7) << 3)]) = k1.s8;
    SW v0, v1;
    v0.u[0] = cvtpk(va[0], va[1]);   v0.u[1] = cvtpk(va[2], va[3]);
    v0.u[2] = cvtpk(va[4], va[5]);   v0.u[3] = cvtpk(va[6], va[7]);
    v1.u[0] = cvtpk(va[8], va[9]);   v1.u[1] = cvtpk(va[10], va[11]);
    v1.u[2] = cvtpk(va[12], va[13]); v1.u[3] = cvtpk(va[14], va[15]);
    short* vt = smem + 16384 + buf * 8192;
    const int ch0 = vs0 >> 3;
    *reinterpret_cast<short8*>(&vt[ve * 128 + (((ch0 + 0) ^ (ve & 7)) << 3)]) = v0.s8;
    *reinterpret_cast<short8*>(&vt[ve * 128 + (((ch0 + 1) ^ (ve & 7)) << 3)]) = v1.s8;
  };

  // one 64q x 128s round (this wave: 16 q x 64 s half), swapped operands
  auto round = [&](int Qb, int str, int curb) {
    const int sb = str * 128 + par * 64;
    const int qtop = Qb + qsub * 16;
    if (sb > qtop + 15) return;
    const short* ktb = smem + curb * 8192;
    const short* vtb = smem + 16384 + curb * 8192;

    // QK^T swapped: D[s][q], col = q = n; 4 cb blocks x k=64
    f32x4 sc[4] = {zero4, zero4, zero4, zero4};
    #pragma unroll
    for (int kc = 0; kc < 2; ++kc) {
      #pragma unroll
      for (int cb = 0; cb < 4; ++cb) {
        const int row = par * 64 + cb * 16 + n;
        const int idx = (row * 64 + kc * 32 + g * 8) ^ ((n & 7) << 3);
        short8 kf = *reinterpret_cast<const short8*>(&ktb[idx]);
        sc[cb] = MFMA16(kf, qf[kc], sc[cb]);
      }
    }

    const int qg = qtop + n;
    if (sb + 63 > qtop) {
      #pragma unroll
      for (int cb = 0; cb < 4; ++cb)
        #pragma unroll
        for (int r = 0; r < 4; ++r)
          if (sb + cb * 16 + sp4 + r > qg) sc[cb][r] = NEGBIG;
    }

    // row max: 15 lane-local + xor16 + xor32
    float m8 = fmaxf(fmaxf(fmaxf(sc[0][0], sc[0][1]), fmaxf(sc[0][2], sc[0][3])),
                     fmaxf(fmaxf(sc[1][0], sc[1][1]), fmaxf(sc[1][2], sc[1][3])));
    m8 = fmaxf(m8, fmaxf(fmaxf(fmaxf(sc[2][0], sc[2][1]), fmaxf(sc[2][2], sc[2][3])),
                         fmaxf(fmaxf(sc[3][0], sc[3][1]), fmaxf(sc[3][2], sc[3][3]))));
    m8 = fmaxf(m8, __shfl_xor(m8, 16));
    m8 = fmaxf(m8, __shfl_xor(m8, 32));

    // exact-identity rescale skip
    const bool resc = !__all(m8 <= mrun);
    if (resc) {
      const float mn = fmaxf(mrun, m8);
      const float afac = exp2v(mrun - mn);
      mrun = mn;
      lrun *= afac;
      #pragma unroll
      for (int e4 = 0; e4 < 4; ++e4)
        #pragma unroll
        for (int r = 0; r < 4; ++r) acc[e4][r] *= afac;
    }

    // P = exp2(S - m) -> packed bf16; per cb: word a (r0,r1), word b (r2,r3)
    unsigned ua[4], ub[4];
    #pragma unroll
    for (int cb = 0; cb < 4; ++cb) {
      ua[cb] = cvtpk(exp2v(sc[cb][0] - mrun), exp2v(sc[cb][1] - mrun));
      ub[cb] = cvtpk(exp2v(sc[cb][2] - mrun), exp2v(sc[cb][3] - mrun));
    }

    // lane^32 exchange per 32-s block -> B-frags in true s order
    SW pw0, pw1;
    {
      const unsigned xa = __shfl_xor(ua[0], 32), xb = __shfl_xor(ub[0], 32);
      const unsigned ya = __shfl_xor(ua[1], 32), yb = __shfl_xor(ub[1], 32);
      pw0.u[0] = glo ? ua[0] : ya;
      pw0.u[1] = glo ? ub[0] : yb;
      pw0.u[2] = glo ? xa : ua[1];
      pw0.u[3] = glo ? xb : ub[1];
    }
    {
      const unsigned xa = __shfl_xor(ua[2], 32), xb = __shfl_xor(ub[2], 32);
      const unsigned ya = __shfl_xor(ua[3], 32), yb = __shfl_xor(ub[3], 32);
      pw1.u[0] = glo ? ua[2] : ya;
      pw1.u[1] = glo ? ub[2] : yb;
      pw1.u[2] = glo ? xa : ua[3];
      pw1.u[3] = glo ? xb : ub[3];
    }

    // PV swapped: acc = V^T x P, two k=32 slices per e-chunk
    #pragma unroll
    for (int e4 = 0; e4 < 4; ++e4) {
      const int e = e4 * 16 + n;
      const int slot0 = (par * 8 + g) ^ (e & 7);
      const int slot1 = (par * 8 + 4 + g) ^ (e & 7);
      short8 vf0 = *reinterpret_cast<const short8*>(&vtb[e * 128 + (slot0 << 3)]);
      acc[e4] = MFMA16(vf0, pw0.s8, acc[e4]);
      short8 vf1 = *reinterpret_cast<const short8*>(&vtb[e * 128 + (slot1 << 3)]);
      acc[e4] = MFMA16(vf1, pw1.s8, acc[e4]);
    }

    // row sum of bf16-rounded P
    float rs = ((bflo(pw0.u[0]) + bfhi(pw0.u[0])) + (bflo(pw0.u[1]) + bfhi(pw0.u[1]))) +
               ((bflo(pw0.u[2]) + bfhi(pw0.u[2])) + (bflo(pw0.u[3]) + bfhi(pw0.u[3])));
    rs += ((bflo(pw1.u[0]) + bfhi(pw1.u[0])) + (bflo(pw1.u[1]) + bfhi(pw1.u[1]))) +
          ((bflo(pw1.u[2]) + bfhi(pw1.u[2])) + (bflo(pw1.u[3]) + bfhi(pw1.u[3])));
    rs += __shfl_xor(rs, 16);
    rs += __shfl_xor(rs, 32);
    lrun += rs;
  };

  // merge parities via scratch overlaid on the retired buffer `curb`
  auto merge_store = [&](int Qb, int curb) {
    float* sA = reinterpret_cast<float*>(smem) + curb * 4096;         // rows 0..31
    float* sB = reinterpret_cast<float*>(smem) + 8192 + curb * 4096;  // rows 32..63 + m + l
    __syncthreads();
    const int row = qsub * 16 + n;
    if (par == 1) {
      float* base = (row < 32) ? (sA + row * 68) : (sB + (row - 32) * 68);
      #pragma unroll
      for (int e4 = 0; e4 < 4; ++e4)
        #pragma unroll
        for (int r = 0; r < 4; ++r) base[e4 * 16 + g * 4 + r] = acc[e4][r];
      if (g == 0) {
        sB[2176 + row] = mrun;
        sB[2240 + row] = lrun;
      }
    }
    __syncthreads();
    if (par == 0) {
      const float* base = (row < 32) ? (sA + row * 68) : (sB + (row - 32) * 68);
      const float m1 = sB[2176 + row];
      const float l1 = sB[2240 + row];
      const float mm = fmaxf(mrun, m1);
      const float a0 = exp2v(mrun - mm);
      const float a1 = exp2v(m1 - mm);
      const float inv = 1.0f / (lrun * a0 + l1 * a1);
      const int q = Qb + row;
      float* op = Og + ((size_t)(b * Lc + q) * Hc + h) * Ec;
      #pragma unroll
      for (int e4 = 0; e4 < 4; ++e4) {
        float4 v;
        v.x = (acc[e4][0] * a0 + base[e4 * 16 + g * 4 + 0] * a1) * inv;
        v.y = (acc[e4][1] * a0 + base[e4 * 16 + g * 4 + 1] * a1) * inv;
        v.z = (acc[e4][2] * a0 + base[e4 * 16 + g * 4 + 2] * a1) * inv;
        v.w = (acc[e4][3] * a0 + base[e4 * 16 + g * 4 + 3] * a1) * inv;
        *reinterpret_cast<float4*>(op + e4 * 16 + g * 4) = v;
      }
    }
  };

  // fused 17-round stream: rounds 0..RL-1 on tile lo, rest on tile hi
  constexpr int NRO = 17;
  loadq(QbL);
  issue(0);
  commit(0);
  __syncthreads();

  int cur = 0;
  for (int rd = 0; rd < NRO; ++rd) {
    const bool pre = (rd + 1 < NRO);
    if (pre) {
      const int nrd = rd + 1;
      const int nstr = (nrd < RL) ? nrd : nrd - RL;
      issue(nstr * 128);
    }
    const bool lo = (rd < RL);
    round(lo ? QbL : QbH, lo ? rd : rd - RL, cur);
    if (rd == RL - 1) {
      merge_store(QbL, cur);   // scratch overlays the just-consumed buffer
      #pragma unroll
      for (int e4 = 0; e4 < 4; ++e4) acc[e4] = zero4;
      mrun = NEGBIG;
      lrun = 0.f;
      loadq(QbH);
    }
    if (pre) commit(cur ^ 1);
    __syncthreads();
    cur ^= 1;
  }

  merge_store(QbH, cur ^ 1);   // last round consumed buffer cur^1 (post-flip)
}

extern "C" void kernel_launch(void* const* d_in, const int* in_sizes, int n_in,
                              void* d_out, int out_size, void* d_ws, size_t ws_size,
                              hipStream_t stream) {
  const float* Q = (const float*)d_in[0];
  const float* K = (const float*)d_in[1];
  const float* V = (const float*)d_in[2];
  float* O = (float*)d_out;
  dim3 grid(Bc * Hc * 16);   // 32 bh x 16 folded pairs, all identical work
  attn_fwd<<<grid, dim3(512), 0, stream>>>(Q, K, V, O);
}

// Round 11
// 90.429 us; speedup vs baseline: 1.8625x; 1.0035x over previous
//
#include <hip/hip_runtime.h>
#include <hip/hip_bf16.h>

typedef __attribute__((ext_vector_type(8))) short short8;
typedef __attribute__((ext_vector_type(4))) float f32x4;
typedef __attribute__((ext_vector_type(2))) unsigned uint2v;

#define MFMA16(a, b, c) __builtin_amdgcn_mfma_f32_16x16x32_bf16((a), (b), (c), 0, 0, 0)

constexpr int Bc = 2, Lc = 2048, Hc = 16, Ec = 64;
constexpr float LOG2E = 1.4426950408889634f;
constexpr float SCALE2 = 0.125f * LOG2E;   // fold log2(e): scores in log2 units
constexpr float NEGBIG = -3.0e38f;

union SW { short8 s8; unsigned u[4]; float4 f4; };

__device__ __forceinline__ unsigned cvtpk(float lo, float hi) {
  unsigned r;
  asm("v_cvt_pk_bf16_f32 %0, %1, %2" : "=v"(r) : "v"(lo), "v"(hi));
  return r;
}
__device__ __forceinline__ float exp2v(float x) {
  float r;
  asm("v_exp_f32 %0, %1" : "=v"(r) : "v"(x));
  return r;
}
__device__ __forceinline__ float bfhi(unsigned u) {
  return __builtin_bit_cast(float, u & 0xffff0000u);
}
__device__ __forceinline__ float bflo(unsigned u) {
  return __builtin_bit_cast(float, u << 16);
}
// SSA builtins: no register-aliasing hazard (r10's asm version coalesced a==b)
__device__ __forceinline__ void plswap32(unsigned& a, unsigned& b) {
  uint2v r = __builtin_amdgcn_permlane32_swap(a, b, false, false);
  a = r[0]; b = r[1];
}
__device__ __forceinline__ void plswap16(unsigned& a, unsigned& b) {
  uint2v r = __builtin_amdgcn_permlane16_swap(a, b, false, false);
  a = r[0]; b = r[1];
}
// butterfly max over lanes {l, l^16, l^32, l^48}, pure VALU
__device__ __forceinline__ float bflymax(float x) {
  unsigned a = __builtin_bit_cast(unsigned, x), b = a;
  plswap16(a, b);
  float y = fmaxf(__builtin_bit_cast(float, a), __builtin_bit_cast(float, b));
  a = __builtin_bit_cast(unsigned, y); b = a;
  plswap32(a, b);
  return fmaxf(__builtin_bit_cast(float, a), __builtin_bit_cast(float, b));
}
__device__ __forceinline__ float bflysum(float x) {
  unsigned a = __builtin_bit_cast(unsigned, x), b = a;
  plswap16(a, b);
  float y = __builtin_bit_cast(float, a) + __builtin_bit_cast(float, b);
  a = __builtin_bit_cast(unsigned, y); b = a;
  plswap32(a, b);
  return __builtin_bit_cast(float, a) + __builtin_bit_cast(float, b);
}

__global__ __launch_bounds__(512, 4)
void attn_fwd(const float* __restrict__ Qg, const float* __restrict__ Kg,
              const float* __restrict__ Vg, float* __restrict__ Og) {
  // smem (shorts), NT=128 s-tile double-buffered:
  //  kt[b]: [128][64] bf16 at b*8192, K row s at prow=pi(s) (bits2<->3),
  //         idx ^ ((prow&7)<<3)
  //  vt[b]: [64 e][128 s] bf16 at 16384 + b*8192, chunk slot = (s>>3) ^ (e&7)
  // merge scratch overlays the RETIRED buffer.
  __shared__ __align__(16) short smem[32768];

  // causal fold: block owns q-tile pair (i, 31-i): exactly 17 uniform rounds
  const int bid = blockIdx.x;
  const int pair = bid & 15;
  const int bh = bid >> 4;
  const int h = bh & (Hc - 1);
  const int b = bh >> 4;
  const int iLo = pair;
  const int QbL = iLo * 64;
  const int QbH = (31 - pair) * 64;
  const int RL = (iLo + 2) >> 1;              // lo-tile rounds; RL + RH = 17

  const int t = threadIdx.x;
  const int w = t >> 6;        // 0..7
  const int qsub = w & 3;      // q sub-block (16 rows)
  const int par = w >> 2;      // 64-s half of the 128-row tile
  const int l = t & 63;
  const int n = l & 15;
  const int g = l >> 4;
  const int sp4 = ((g & 1) << 3) | ((g >> 1) << 2);  // pi(g)*4

  const f32x4 zero4 = {0.f, 0.f, 0.f, 0.f};

  // Q fragments (B-operand: col=q=lane&15, k=e=(lane>>4)*8+j)
  short8 qf[2];
  auto loadq = [&](int Qb) {
    const int q = Qb + qsub * 16 + n;
    const float* qp = Qg + ((size_t)(b * Lc + q) * Hc + h) * Ec + g * 8;
    SW a0, a1, b0, b1, r0, r1;
    a0.f4 = reinterpret_cast<const float4*>(qp)[0];
    a1.f4 = reinterpret_cast<const float4*>(qp)[1];
    b0.f4 = reinterpret_cast<const float4*>(qp + 32)[0];
    b1.f4 = reinterpret_cast<const float4*>(qp + 32)[1];
    r0.u[0] = cvtpk(a0.f4.x * SCALE2, a0.f4.y * SCALE2);
    r0.u[1] = cvtpk(a0.f4.z * SCALE2, a0.f4.w * SCALE2);
    r0.u[2] = cvtpk(a1.f4.x * SCALE2, a1.f4.y * SCALE2);
    r0.u[3] = cvtpk(a1.f4.z * SCALE2, a1.f4.w * SCALE2);
    r1.u[0] = cvtpk(b0.f4.x * SCALE2, b0.f4.y * SCALE2);
    r1.u[1] = cvtpk(b0.f4.z * SCALE2, b0.f4.w * SCALE2);
    r1.u[2] = cvtpk(b1.f4.x * SCALE2, b1.f4.y * SCALE2);
    r1.u[3] = cvtpk(b1.f4.z * SCALE2, b1.f4.w * SCALE2);
    qf[0] = r0.s8;
    qf[1] = r1.s8;
  };

  // acc[e4][r] = O^T[e = e4*16 + g*4 + r][q = n]; per-lane scalar m,l
  f32x4 acc[4] = {zero4, zero4, zero4, zero4};
  float mrun = NEGBIG, lrun = 0.f;

  // staging: 512 threads stage 128 rows of K (pi-permuted) and V^T per round
  const int srow = t >> 2;                               // 0..127
  const int prow = (srow & ~12) | ((srow & 4) << 1) | ((srow & 8) >> 1);
  const int kc0 = (t & 3) * 16;                          // 16-float column chunk
  const int ve = l, vs0 = w * 16;                        // V^T: e=lane, 16 s rows

  float4 ka[4];
  float va[16];

  auto issue = [&](int r0) {
    const float* kp = Kg + ((size_t)(b * Lc + r0 + srow) * Hc + h) * Ec + kc0;
    ka[0] = reinterpret_cast<const float4*>(kp)[0];
    ka[1] = reinterpret_cast<const float4*>(kp)[1];
    ka[2] = reinterpret_cast<const float4*>(kp)[2];
    ka[3] = reinterpret_cast<const float4*>(kp)[3];
    const float* vp = Vg + ((size_t)(b * Lc + r0 + vs0) * Hc + h) * Ec + ve;
    #pragma unroll
    for (int j = 0; j < 16; ++j) va[j] = vp[(size_t)j * (Hc * Ec)];
  };
  auto commit = [&](int buf) {
    SW k0, k1;
    k0.u[0] = cvtpk(ka[0].x, ka[0].y); k0.u[1] = cvtpk(ka[0].z, ka[0].w);
    k0.u[2] = cvtpk(ka[1].x, ka[1].y); k0.u[3] = cvtpk(ka[1].z, ka[1].w);
    k1.u[0] = cvtpk(ka[2].x, ka[2].y); k1.u[1] = cvtpk(ka[2].z, ka[2].w);
    k1.u[2] = cvtpk(ka[3].x, ka[3].y); k1.u[3] = cvtpk(ka[3].z, ka[3].w);
    short* kt = smem + buf * 8192;
    *reinterpret_cast<short8*>(&kt[(prow * 64 + kc0) ^ ((prow & 7) << 3)]) = k0.s8;
    *reinterpret_cast<short8*>(&kt[(prow * 64 + kc0 + 8) ^ ((prow & 7) << 3)]) = k1.s8;
    SW v0, v1;
    v0.u[0] = cvtpk(va[0], va[1]);   v0.u[1] = cvtpk(va[2], va[3]);
    v0.u[2] = cvtpk(va[4], va[5]);   v0.u[3] = cvtpk(va[6], va[7]);
    v1.u[0] = cvtpk(va[8], va[9]);   v1.u[1] = cvtpk(va[10], va[11]);
    v1.u[2] = cvtpk(va[12], va[13]); v1.u[3] = cvtpk(va[14], va[15]);
    short* vt = smem + 16384 + buf * 8192;
    const int ch0 = vs0 >> 3;
    *reinterpret_cast<short8*>(&vt[ve * 128 + (((ch0 + 0) ^ (ve & 7)) << 3)]) = v0.s8;
    *reinterpret_cast<short8*>(&vt[ve * 128 + (((ch0 + 1) ^ (ve & 7)) << 3)]) = v1.s8;
  };

  // one 64q x 128s round (this wave: 16 q x 64 s half), swapped operands
  auto round = [&](int Qb, int str, int curb) {
    const int sb = str * 128 + par * 64;
    const int qtop = Qb + qsub * 16;
    if (sb > qtop + 15) return;
    const short* ktb = smem + curb * 8192;
    const short* vtb = smem + 16384 + curb * 8192;

    // QK^T swapped: D[s][q], col = q = n; 4 cb blocks x k=64
    f32x4 sc[4] = {zero4, zero4, zero4, zero4};
    #pragma unroll
    for (int kc = 0; kc < 2; ++kc) {
      #pragma unroll
      for (int cb = 0; cb < 4; ++cb) {
        const int row = par * 64 + cb * 16 + n;
        const int idx = (row * 64 + kc * 32 + g * 8) ^ ((n & 7) << 3);
        short8 kf = *reinterpret_cast<const short8*>(&ktb[idx]);
        sc[cb] = MFMA16(kf, qf[kc], sc[cb]);
      }
    }

    const int qg = qtop + n;
    if (sb + 63 > qtop) {
      #pragma unroll
      for (int cb = 0; cb < 4; ++cb)
        #pragma unroll
        for (int r = 0; r < 4; ++r)
          if (sb + cb * 16 + sp4 + r > qg) sc[cb][r] = NEGBIG;
    }

    // row max: 15 lane-local fmax + VALU butterfly (permlane swaps)
    float m8 = fmaxf(fmaxf(fmaxf(sc[0][0], sc[0][1]), fmaxf(sc[0][2], sc[0][3])),
                     fmaxf(fmaxf(sc[1][0], sc[1][1]), fmaxf(sc[1][2], sc[1][3])));
    m8 = fmaxf(m8, fmaxf(fmaxf(fmaxf(sc[2][0], sc[2][1]), fmaxf(sc[2][2], sc[2][3])),
                         fmaxf(fmaxf(sc[3][0], sc[3][1]), fmaxf(sc[3][2], sc[3][3]))));
    m8 = bflymax(m8);

    // exact-identity rescale skip
    const bool resc = !__all(m8 <= mrun);
    if (resc) {
      const float mn = fmaxf(mrun, m8);
      const float afac = exp2v(mrun - mn);
      mrun = mn;
      lrun *= afac;
      #pragma unroll
      for (int e4 = 0; e4 < 4; ++e4)
        #pragma unroll
        for (int r = 0; r < 4; ++r) acc[e4][r] *= afac;
    }

    // P = exp2(S - m) -> packed bf16; per cb: word a (r0,r1), word b (r2,r3)
    unsigned ua[4], ub[4];
    #pragma unroll
    for (int cb = 0; cb < 4; ++cb) {
      ua[cb] = cvtpk(exp2v(sc[cb][0] - mrun), exp2v(sc[cb][1] - mrun));
      ub[cb] = cvtpk(exp2v(sc[cb][2] - mrun), exp2v(sc[cb][3] - mrun));
    }

    // P C-frag -> B-frag: pure-VALU permlane32 swaps (word-exact vs r9 shfl)
    plswap32(ua[0], ua[1]);
    plswap32(ub[0], ub[1]);
    plswap32(ua[2], ua[3]);
    plswap32(ub[2], ub[3]);
    SW pw0, pw1;
    pw0.u[0] = ua[0]; pw0.u[1] = ub[0]; pw0.u[2] = ua[1]; pw0.u[3] = ub[1];
    pw1.u[0] = ua[2]; pw1.u[1] = ub[2]; pw1.u[2] = ua[3]; pw1.u[3] = ub[3];

    // PV swapped: acc = V^T x P, two k=32 slices per e-chunk
    #pragma unroll
    for (int e4 = 0; e4 < 4; ++e4) {
      const int e = e4 * 16 + n;
      const int slot0 = (par * 8 + g) ^ (e & 7);
      const int slot1 = (par * 8 + 4 + g) ^ (e & 7);
      short8 vf0 = *reinterpret_cast<const short8*>(&vtb[e * 128 + (slot0 << 3)]);
      acc[e4] = MFMA16(vf0, pw0.s8, acc[e4]);
      short8 vf1 = *reinterpret_cast<const short8*>(&vtb[e * 128 + (slot1 << 3)]);
      acc[e4] = MFMA16(vf1, pw1.s8, acc[e4]);
    }

    // row sum of bf16-rounded P + VALU butterfly
    float rs = ((bflo(pw0.u[0]) + bfhi(pw0.u[0])) + (bflo(pw0.u[1]) + bfhi(pw0.u[1]))) +
               ((bflo(pw0.u[2]) + bfhi(pw0.u[2])) + (bflo(pw0.u[3]) + bfhi(pw0.u[3])));
    rs += ((bflo(pw1.u[0]) + bfhi(pw1.u[0])) + (bflo(pw1.u[1]) + bfhi(pw1.u[1]))) +
          ((bflo(pw1.u[2]) + bfhi(pw1.u[2])) + (bflo(pw1.u[3]) + bfhi(pw1.u[3])));
    lrun += bflysum(rs);
  };

  // merge parities via scratch overlaid on the retired buffer `curb`
  auto merge_store = [&](int Qb, int curb) {
    float* sA = reinterpret_cast<float*>(smem) + curb * 4096;         // rows 0..31
    float* sB = reinterpret_cast<float*>(smem) + 8192 + curb * 4096;  // rows 32..63 + m + l
    __syncthreads();
    const int row = qsub * 16 + n;
    if (par == 1) {
      float* base = (row < 32) ? (sA + row * 68) : (sB + (row - 32) * 68);
      #pragma unroll
      for (int e4 = 0; e4 < 4; ++e4)
        #pragma unroll
        for (int r = 0; r < 4; ++r) base[e4 * 16 + g * 4 + r] = acc[e4][r];
      if (g == 0) {
        sB[2176 + row] = mrun;
        sB[2240 + row] = lrun;
      }
    }
    __syncthreads();
    if (par == 0) {
      const float* base = (row < 32) ? (sA + row * 68) : (sB + (row - 32) * 68);
      const float m1 = sB[2176 + row];
      const float l1 = sB[2240 + row];
      const float mm = fmaxf(mrun, m1);
      const float a0 = exp2v(mrun - mm);
      const float a1 = exp2v(m1 - mm);
      const float inv = 1.0f / (lrun * a0 + l1 * a1);
      const int q = Qb + row;
      float* op = Og + ((size_t)(b * Lc + q) * Hc + h) * Ec;
      #pragma unroll
      for (int e4 = 0; e4 < 4; ++e4) {
        float4 v;
        v.x = (acc[e4][0] * a0 + base[e4 * 16 + g * 4 + 0] * a1) * inv;
        v.y = (acc[e4][1] * a0 + base[e4 * 16 + g * 4 + 1] * a1) * inv;
        v.z = (acc[e4][2] * a0 + base[e4 * 16 + g * 4 + 2] * a1) * inv;
        v.w = (acc[e4][3] * a0 + base[e4 * 16 + g * 4 + 3] * a1) * inv;
        *reinterpret_cast<float4*>(op + e4 * 16 + g * 4) = v;
      }
    }
  };

  // fused 17-round stream: rounds 0..RL-1 on tile lo, rest on tile hi
  constexpr int NRO = 17;
  loadq(QbL);
  issue(0);
  commit(0);
  __syncthreads();

  int cur = 0;
  for (int rd = 0; rd < NRO; ++rd) {
    const bool pre = (rd + 1 < NRO);
    if (pre) {
      const int nrd = rd + 1;
      const int nstr = (nrd < RL) ? nrd : nrd - RL;
      issue(nstr * 128);
    }
    const bool lo = (rd < RL);
    round(lo ? QbL : QbH, lo ? rd : rd - RL, cur);
    if (rd == RL - 1) {
      merge_store(QbL, cur);   // scratch overlays the just-consumed buffer
      #pragma unroll
      for (int e4 = 0; e4 < 4; ++e4) acc[e4] = zero4;
      mrun = NEGBIG;
      lrun = 0.f;
      loadq(QbH);
    }
    if (pre) commit(cur ^ 1);
    __syncthreads();
    cur ^= 1;
  }

  merge_store(QbH, cur ^ 1);   // last round consumed buffer cur^1 (post-flip)
}

extern "C" void kernel_launch(void* const* d_in, const int* in_sizes, int n_in,
                              void* d_out, int out_size, void* d_ws, size_t ws_size,
                              hipStream_t stream) {
  const float* Q = (const float*)d_in[0];
  const float* K = (const float*)d_in[1];
  const float* V = (const float*)d_in[2];
  float* O = (float*)d_out;
  dim3 grid(Bc * Hc * 16);   // 32 bh x 16 folded pairs, all identical work
  attn_fwd<<<grid, dim3(512), 0, stream>>>(Q, K, V, O);
}

// Round 12
// 87.133 us; speedup vs baseline: 1.9329x; 1.0378x over previous
//
#include <hip/hip_runtime.h>
#include <hip/hip_bf16.h>

typedef __attribute__((ext_vector_type(8))) short short8;
typedef __attribute__((ext_vector_type(4))) float f32x4;
typedef __attribute__((ext_vector_type(2))) unsigned uint2v;

#define MFMA16(a, b, c) __builtin_amdgcn_mfma_f32_16x16x32_bf16((a), (b), (c), 0, 0, 0)

constexpr int Bc = 2, Lc = 2048, Hc = 16, Ec = 64;
constexpr float LOG2E = 1.4426950408889634f;
constexpr float SCALE2 = 0.125f * LOG2E;   // fold log2(e): scores in log2 units
constexpr float NEGBIG = -3.0e38f;

union SW { short8 s8; unsigned u[4]; float4 f4; };

__device__ __forceinline__ unsigned cvtpk(float lo, float hi) {
  unsigned r;
  asm("v_cvt_pk_bf16_f32 %0, %1, %2" : "=v"(r) : "v"(lo), "v"(hi));
  return r;
}
__device__ __forceinline__ float exp2v(float x) {
  float r;
  asm("v_exp_f32 %0, %1" : "=v"(r) : "v"(x));
  return r;
}
__device__ __forceinline__ float bfhi(unsigned u) {
  return __builtin_bit_cast(float, u & 0xffff0000u);
}
__device__ __forceinline__ float bflo(unsigned u) {
  return __builtin_bit_cast(float, u << 16);
}
// SSA builtins: no register-aliasing hazard (r10's asm version coalesced a==b)
__device__ __forceinline__ void plswap32(unsigned& a, unsigned& b) {
  uint2v r = __builtin_amdgcn_permlane32_swap(a, b, false, false);
  a = r[0]; b = r[1];
}
__device__ __forceinline__ void plswap16(unsigned& a, unsigned& b) {
  uint2v r = __builtin_amdgcn_permlane16_swap(a, b, false, false);
  a = r[0]; b = r[1];
}
// butterfly max over lanes {l, l^16, l^32, l^48}, pure VALU
__device__ __forceinline__ float bflymax(float x) {
  unsigned a = __builtin_bit_cast(unsigned, x), b = a;
  plswap16(a, b);
  float y = fmaxf(__builtin_bit_cast(float, a), __builtin_bit_cast(float, b));
  a = __builtin_bit_cast(unsigned, y); b = a;
  plswap32(a, b);
  return fmaxf(__builtin_bit_cast(float, a), __builtin_bit_cast(float, b));
}
__device__ __forceinline__ float bflysum(float x) {
  unsigned a = __builtin_bit_cast(unsigned, x), b = a;
  plswap16(a, b);
  float y = __builtin_bit_cast(float, a) + __builtin_bit_cast(float, b);
  a = __builtin_bit_cast(unsigned, y); b = a;
  plswap32(a, b);
  return __builtin_bit_cast(float, a) + __builtin_bit_cast(float, b);
}

__global__ __launch_bounds__(512, 2)
void attn_fwd(const float* __restrict__ Qg, const float* __restrict__ Kg,
              const float* __restrict__ Vg, float* __restrict__ Og) {
  // smem (shorts), NT=128 s-tile double-buffered:
  //  kt[b]: [128][64] bf16 at b*8192, K row s at prow=pi(s) (bits2<->3),
  //         idx ^ ((prow&7)<<3)
  //  vt[b]: [64 e][128 s] bf16 at 16384 + b*8192, chunk slot = (s>>3) ^ (e&7)
  // merge scratch overlays the RETIRED buffer.
  __shared__ __align__(16) short smem[32768];

  // causal fold: block owns q-tile pair (i, 31-i): exactly 17 uniform rounds
  const int bid = blockIdx.x;
  const int pair = bid & 15;
  const int bh = bid >> 4;
  const int h = bh & (Hc - 1);
  const int b = bh >> 4;
  const int iLo = pair;
  const int QbL = iLo * 64;
  const int QbH = (31 - pair) * 64;
  const int RL = (iLo + 2) >> 1;              // lo-tile rounds; RL + RH = 17

  const int t = threadIdx.x;
  const int w = t >> 6;        // 0..7
  const int qsub = w & 3;      // q sub-block (16 rows)
  const int par = w >> 2;      // 64-s half of the 128-row tile
  const int l = t & 63;
  const int n = l & 15;
  const int g = l >> 4;
  const int sp4 = ((g & 1) << 3) | ((g >> 1) << 2);  // pi(g)*4

  const f32x4 zero4 = {0.f, 0.f, 0.f, 0.f};

  // Q fragments (B-operand: col=q=lane&15, k=e=(lane>>4)*8+j)
  short8 qf[2];
  auto loadq = [&](int Qb) {
    const int q = Qb + qsub * 16 + n;
    const float* qp = Qg + ((size_t)(b * Lc + q) * Hc + h) * Ec + g * 8;
    SW a0, a1, b0, b1, r0, r1;
    a0.f4 = reinterpret_cast<const float4*>(qp)[0];
    a1.f4 = reinterpret_cast<const float4*>(qp)[1];
    b0.f4 = reinterpret_cast<const float4*>(qp + 32)[0];
    b1.f4 = reinterpret_cast<const float4*>(qp + 32)[1];
    r0.u[0] = cvtpk(a0.f4.x * SCALE2, a0.f4.y * SCALE2);
    r0.u[1] = cvtpk(a0.f4.z * SCALE2, a0.f4.w * SCALE2);
    r0.u[2] = cvtpk(a1.f4.x * SCALE2, a1.f4.y * SCALE2);
    r0.u[3] = cvtpk(a1.f4.z * SCALE2, a1.f4.w * SCALE2);
    r1.u[0] = cvtpk(b0.f4.x * SCALE2, b0.f4.y * SCALE2);
    r1.u[1] = cvtpk(b0.f4.z * SCALE2, b0.f4.w * SCALE2);
    r1.u[2] = cvtpk(b1.f4.x * SCALE2, b1.f4.y * SCALE2);
    r1.u[3] = cvtpk(b1.f4.z * SCALE2, b1.f4.w * SCALE2);
    qf[0] = r0.s8;
    qf[1] = r1.s8;
  };

  // acc[e4][r] = O^T[e = e4*16 + g*4 + r][q = n]; per-lane scalar m,l
  f32x4 acc[4] = {zero4, zero4, zero4, zero4};
  float mrun = NEGBIG, lrun = 0.f;

  // staging: 512 threads stage 128 rows of K (pi-permuted) and V^T per round
  const int srow = t >> 2;                               // 0..127
  const int prow = (srow & ~12) | ((srow & 4) << 1) | ((srow & 8) >> 1);
  const int kc0 = (t & 3) * 16;                          // 16-float column chunk
  const int ve = l, vs0 = w * 16;                        // V^T: e=lane, 16 s rows

  float4 ka[4];
  float va[16];

  auto issue = [&](int r0) {
    const float* kp = Kg + ((size_t)(b * Lc + r0 + srow) * Hc + h) * Ec + kc0;
    ka[0] = reinterpret_cast<const float4*>(kp)[0];
    ka[1] = reinterpret_cast<const float4*>(kp)[1];
    ka[2] = reinterpret_cast<const float4*>(kp)[2];
    ka[3] = reinterpret_cast<const float4*>(kp)[3];
    const float* vp = Vg + ((size_t)(b * Lc + r0 + vs0) * Hc + h) * Ec + ve;
    #pragma unroll
    for (int j = 0; j < 16; ++j) va[j] = vp[(size_t)j * (Hc * Ec)];
  };
  auto commit = [&](int buf) {
    SW k0, k1;
    k0.u[0] = cvtpk(ka[0].x, ka[0].y); k0.u[1] = cvtpk(ka[0].z, ka[0].w);
    k0.u[2] = cvtpk(ka[1].x, ka[1].y); k0.u[3] = cvtpk(ka[1].z, ka[1].w);
    k1.u[0] = cvtpk(ka[2].x, ka[2].y); k1.u[1] = cvtpk(ka[2].z, ka[2].w);
    k1.u[2] = cvtpk(ka[3].x, ka[3].y); k1.u[3] = cvtpk(ka[3].z, ka[3].w);
    short* kt = smem + buf * 8192;
    *reinterpret_cast<short8*>(&kt[(prow * 64 + kc0) ^ ((prow & 7) << 3)]) = k0.s8;
    *reinterpret_cast<short8*>(&kt[(prow * 64 + kc0 + 8) ^ ((prow & 7) << 3)]) = k1.s8;
    SW v0, v1;
    v0.u[0] = cvtpk(va[0], va[1]);   v0.u[1] = cvtpk(va[2], va[3]);
    v0.u[2] = cvtpk(va[4], va[5]);   v0.u[3] = cvtpk(va[6], va[7]);
    v1.u[0] = cvtpk(va[8], va[9]);   v1.u[1] = cvtpk(va[10], va[11]);
    v1.u[2] = cvtpk(va[12], va[13]); v1.u[3] = cvtpk(va[14], va[15]);
    short* vt = smem + 16384 + buf * 8192;
    const int ch0 = vs0 >> 3;
    *reinterpret_cast<short8*>(&vt[ve * 128 + (((ch0 + 0) ^ (ve & 7)) << 3)]) = v0.s8;
    *reinterpret_cast<short8*>(&vt[ve * 128 + (((ch0 + 1) ^ (ve & 7)) << 3)]) = v1.s8;
  };

  // one 64q x 128s round (this wave: 16 q x 64 s half), swapped operands
  auto round = [&](int Qb, int str, int curb) {
    const int sb = str * 128 + par * 64;
    const int qtop = Qb + qsub * 16;
    if (sb > qtop + 15) return;
    const short* ktb = smem + curb * 8192;
    const short* vtb = smem + 16384 + curb * 8192;

    // QK^T swapped: D[s][q], col = q = n; 4 cb blocks x k=64
    f32x4 sc[4] = {zero4, zero4, zero4, zero4};
    #pragma unroll
    for (int kc = 0; kc < 2; ++kc) {
      #pragma unroll
      for (int cb = 0; cb < 4; ++cb) {
        const int row = par * 64 + cb * 16 + n;
        const int idx = (row * 64 + kc * 32 + g * 8) ^ ((n & 7) << 3);
        short8 kf = *reinterpret_cast<const short8*>(&ktb[idx]);
        sc[cb] = MFMA16(kf, qf[kc], sc[cb]);
      }
    }

    const int qg = qtop + n;
    if (sb + 63 > qtop) {
      #pragma unroll
      for (int cb = 0; cb < 4; ++cb)
        #pragma unroll
        for (int r = 0; r < 4; ++r)
          if (sb + cb * 16 + sp4 + r > qg) sc[cb][r] = NEGBIG;
    }

    // row max: 15 lane-local fmax + VALU butterfly (permlane swaps)
    float m8 = fmaxf(fmaxf(fmaxf(sc[0][0], sc[0][1]), fmaxf(sc[0][2], sc[0][3])),
                     fmaxf(fmaxf(sc[1][0], sc[1][1]), fmaxf(sc[1][2], sc[1][3])));
    m8 = fmaxf(m8, fmaxf(fmaxf(fmaxf(sc[2][0], sc[2][1]), fmaxf(sc[2][2], sc[2][3])),
                         fmaxf(fmaxf(sc[3][0], sc[3][1]), fmaxf(sc[3][2], sc[3][3]))));
    m8 = bflymax(m8);

    // exact-identity rescale skip
    const bool resc = !__all(m8 <= mrun);
    if (resc) {
      const float mn = fmaxf(mrun, m8);
      const float afac = exp2v(mrun - mn);
      mrun = mn;
      lrun *= afac;
      #pragma unroll
      for (int e4 = 0; e4 < 4; ++e4)
        #pragma unroll
        for (int r = 0; r < 4; ++r) acc[e4][r] *= afac;
    }

    // P = exp2(S - m) -> packed bf16; per cb: word a (r0,r1), word b (r2,r3)
    unsigned ua[4], ub[4];
    #pragma unroll
    for (int cb = 0; cb < 4; ++cb) {
      ua[cb] = cvtpk(exp2v(sc[cb][0] - mrun), exp2v(sc[cb][1] - mrun));
      ub[cb] = cvtpk(exp2v(sc[cb][2] - mrun), exp2v(sc[cb][3] - mrun));
    }

    // P C-frag -> B-frag: pure-VALU permlane32 swaps (word-exact vs r9 shfl)
    plswap32(ua[0], ua[1]);
    plswap32(ub[0], ub[1]);
    plswap32(ua[2], ua[3]);
    plswap32(ub[2], ub[3]);
    SW pw0, pw1;
    pw0.u[0] = ua[0]; pw0.u[1] = ub[0]; pw0.u[2] = ua[1]; pw0.u[3] = ub[1];
    pw1.u[0] = ua[2]; pw1.u[1] = ub[2]; pw1.u[2] = ua[3]; pw1.u[3] = ub[3];

    // PV swapped: acc = V^T x P, two k=32 slices per e-chunk
    #pragma unroll
    for (int e4 = 0; e4 < 4; ++e4) {
      const int e = e4 * 16 + n;
      const int slot0 = (par * 8 + g) ^ (e & 7);
      const int slot1 = (par * 8 + 4 + g) ^ (e & 7);
      short8 vf0 = *reinterpret_cast<const short8*>(&vtb[e * 128 + (slot0 << 3)]);
      acc[e4] = MFMA16(vf0, pw0.s8, acc[e4]);
      short8 vf1 = *reinterpret_cast<const short8*>(&vtb[e * 128 + (slot1 << 3)]);
      acc[e4] = MFMA16(vf1, pw1.s8, acc[e4]);
    }

    // row sum of bf16-rounded P + VALU butterfly
    float rs = ((bflo(pw0.u[0]) + bfhi(pw0.u[0])) + (bflo(pw0.u[1]) + bfhi(pw0.u[1]))) +
               ((bflo(pw0.u[2]) + bfhi(pw0.u[2])) + (bflo(pw0.u[3]) + bfhi(pw0.u[3])));
    rs += ((bflo(pw1.u[0]) + bfhi(pw1.u[0])) + (bflo(pw1.u[1]) + bfhi(pw1.u[1]))) +
          ((bflo(pw1.u[2]) + bfhi(pw1.u[2])) + (bflo(pw1.u[3]) + bfhi(pw1.u[3])));
    lrun += bflysum(rs);
  };

  // merge parities via scratch overlaid on the retired buffer `curb`
  auto merge_store = [&](int Qb, int curb) {
    float* sA = reinterpret_cast<float*>(smem) + curb * 4096;         // rows 0..31
    float* sB = reinterpret_cast<float*>(smem) + 8192 + curb * 4096;  // rows 32..63 + m + l
    __syncthreads();
    const int row = qsub * 16 + n;
    if (par == 1) {
      float* base = (row < 32) ? (sA + row * 68) : (sB + (row - 32) * 68);
      #pragma unroll
      for (int e4 = 0; e4 < 4; ++e4)
        #pragma unroll
        for (int r = 0; r < 4; ++r) base[e4 * 16 + g * 4 + r] = acc[e4][r];
      if (g == 0) {
        sB[2176 + row] = mrun;
        sB[2240 + row] = lrun;
      }
    }
    __syncthreads();
    if (par == 0) {
      const float* base = (row < 32) ? (sA + row * 68) : (sB + (row - 32) * 68);
      const float m1 = sB[2176 + row];
      const float l1 = sB[2240 + row];
      const float mm = fmaxf(mrun, m1);
      const float a0 = exp2v(mrun - mm);
      const float a1 = exp2v(m1 - mm);
      const float inv = 1.0f / (lrun * a0 + l1 * a1);
      const int q = Qb + row;
      float* op = Og + ((size_t)(b * Lc + q) * Hc + h) * Ec;
      #pragma unroll
      for (int e4 = 0; e4 < 4; ++e4) {
        float4 v;
        v.x = (acc[e4][0] * a0 + base[e4 * 16 + g * 4 + 0] * a1) * inv;
        v.y = (acc[e4][1] * a0 + base[e4 * 16 + g * 4 + 1] * a1) * inv;
        v.z = (acc[e4][2] * a0 + base[e4 * 16 + g * 4 + 2] * a1) * inv;
        v.w = (acc[e4][3] * a0 + base[e4 * 16 + g * 4 + 3] * a1) * inv;
        *reinterpret_cast<float4*>(op + e4 * 16 + g * 4) = v;
      }
    }
  };

  // fused 17-round stream: rounds 0..RL-1 on tile lo, rest on tile hi
  constexpr int NRO = 17;
  loadq(QbL);
  issue(0);
  commit(0);
  __syncthreads();

  int cur = 0;
  for (int rd = 0; rd < NRO; ++rd) {
    const bool pre = (rd + 1 < NRO);
    if (pre) {
      const int nrd = rd + 1;
      const int nstr = (nrd < RL) ? nrd : nrd - RL;
      issue(nstr * 128);
    }
    const bool lo = (rd < RL);
    round(lo ? QbL : QbH, lo ? rd : rd - RL, cur);
    if (rd == RL - 1) {
      merge_store(QbL, cur);   // scratch overlays the just-consumed buffer
      #pragma unroll
      for (int e4 = 0; e4 < 4; ++e4) acc[e4] = zero4;
      mrun = NEGBIG;
      lrun = 0.f;
      loadq(QbH);
    }
    if (pre) commit(cur ^ 1);
    __syncthreads();
    cur ^= 1;
  }

  merge_store(QbH, cur ^ 1);   // last round consumed buffer cur^1 (post-flip)
}

extern "C" void kernel_launch(void* const* d_in, const int* in_sizes, int n_in,
                              void* d_out, int out_size, void* d_ws, size_t ws_size,
                              hipStream_t stream) {
  const float* Q = (const float*)d_in[0];
  const float* K = (const float*)d_in[1];
  const float* V = (const float*)d_in[2];
  float* O = (float*)d_out;
  dim3 grid(Bc * Hc * 16);   // 32 bh x 16 folded pairs, all identical work
  attn_fwd<<<grid, dim3(512), 0, stream>>>(Q, K, V, O);
}